// Round 7
// baseline (484.944 us; speedup 1.0000x reference)
//
#include <hip/hip_runtime.h>
#include <hip/hip_bf16.h>

#define N_NODES 50000
#define N_EDGES 800000
#define FDIM    128
#define HEADS   8
#define HID     16
#define NCLS    10
#define SCB     512   // scan block size
#define NPART   8     // XCD partitions for the CSR scatter
#define PSZ     6250  // N_NODES / NPART

typedef unsigned short u16;
typedef __attribute__((ext_vector_type(8))) short bf16x8;
typedef __attribute__((ext_vector_type(4))) float f32x4;

__device__ __forceinline__ float bf2f(u16 u) {
    union { unsigned int i; float f; } c; c.i = ((unsigned int)u) << 16; return c.f;
}
__device__ __forceinline__ u16 f2bf(float f) {
    union { float f; unsigned int i; } c; c.f = f;
    unsigned int r = c.i + 0x7FFFu + ((c.i >> 16) & 1u);
    return (u16)(r >> 16);
}
__device__ __forceinline__ float4 bf2f4(ushort4 u) {
    return make_float4(bf2f(u.x), bf2f(u.y), bf2f(u.z), bf2f(u.w));
}
__device__ __forceinline__ float  ldf(const float* p) { return *p; }
__device__ __forceinline__ float  ldf(const u16* p)   { return bf2f(*p); }
__device__ __forceinline__ float4 ld4f(const float* p){ return *(const float4*)p; }
__device__ __forceinline__ float4 ld4f(const u16* p)  { return bf2f4(*(const ushort4*)p); }
__device__ __forceinline__ void   st2(float* p, float a, float b) {
    *(float2*)p = make_float2(a, b);
}
__device__ __forceinline__ void   st2(u16* p, float a, float b) {
    unsigned int u = (unsigned int)f2bf(a) | ((unsigned int)f2bf(b) << 16);
    *(unsigned int*)p = u;
}
__device__ __forceinline__ void   st4(float* p, float4 v) { *(float4*)p = v; }
__device__ __forceinline__ void   st4(u16* p, float4 v) {
    ushort4 u; u.x = f2bf(v.x); u.y = f2bf(v.y); u.z = f2bf(v.z); u.w = f2bf(v.w);
    *(ushort4*)p = u;
}

// external-input decode (dtype resolved at runtime via flag)
__device__ __forceinline__ float ldin(const void* p, int i, bool isf32) {
    return isf32 ? ((const float*)p)[i] : bf2f(((const u16*)p)[i]);
}
__device__ __forceinline__ float4 ldin4(const void* p, int i4, bool isf32) {
    if (isf32) return ((const float4*)p)[i4];
    return bf2f4(((const ushort4*)p)[i4]);
}

// ---------------- dtype detection (W0 scan) ----------------
__global__ void detect_dtype(const u16* __restrict__ w, int n, int* __restrict__ flag) {
    __shared__ int s_huge, s_zero;
    if (threadIdx.x == 0) { s_huge = 0; s_zero = 0; }
    __syncthreads();
    int huge = 0, zero = 0;
    for (int i = threadIdx.x; i < n; i += 256) {
        u16 b = w[i];
        float v = bf2f(b);
        if (fabsf(v) > 1e9f || v != v) huge++;
        if (b == 0) zero++;
    }
    atomicAdd(&s_huge, huge);
    atomicAdd(&s_zero, zero);
    __syncthreads();
    if (threadIdx.x == 0)
        *flag = (s_huge > 0 || s_zero > n / 4) ? 1 : 0;
}

// ---------------- W transpose to bf16 (Wt[n][k]) for MFMA B-frags ----------------
__global__ void prep_wt(const void* __restrict__ W0, const void* __restrict__ W1,
                        const void* __restrict__ W2, const void* __restrict__ W3,
                        u16* __restrict__ Wt, const int* __restrict__ dflag) {
    const bool isf32 = (*dflag != 0);
    int l = blockIdx.y;
    const void* W = (l == 0) ? W0 : (l == 1) ? W1 : (l == 2) ? W2 : W3;
    int i = blockIdx.x * 256 + threadIdx.x;
    if (i >= FDIM * FDIM) return;
    int n = i >> 7, k = i & 127;
    Wt[l * FDIM * FDIM + n * FDIM + k] = f2bf(ldin(W, k * FDIM + n, isf32));
}

// ---------------- CSR build ----------------

__global__ void zero_int(int* p, int n) {
    int i = blockIdx.x * blockDim.x + threadIdx.x;
    if (i < n) p[i] = 0;
}

__global__ void count_deg(const int* __restrict__ dst, int* __restrict__ deg) {
    int i = blockIdx.x * blockDim.x + threadIdx.x;
    if (i < N_EDGES) atomicAdd(&deg[dst[i]], 1);
}

__global__ void __launch_bounds__(SCB)
deg_bsum(const int* __restrict__ deg, int* __restrict__ bsum) {
    int i = blockIdx.x * SCB + threadIdx.x;
    int v = (i < N_NODES) ? deg[i] : 0;
    for (int off = 32; off; off >>= 1) v += __shfl_down(v, off, 64);
    __shared__ int wsum[SCB / 64];
    int wv = threadIdx.x >> 6, ln = threadIdx.x & 63;
    if (ln == 0) wsum[wv] = v;
    __syncthreads();
    if (threadIdx.x == 0) {
        int s = 0;
        #pragma unroll
        for (int k = 0; k < SCB / 64; k++) s += wsum[k];
        bsum[blockIdx.x] = s;
    }
}

__global__ void scan_bsum(int* __restrict__ bsum, int nb, int* __restrict__ row_ptr) {
    int ln = threadIdx.x;  // 64 threads, nb <= 128
    int o0 = (ln < nb) ? bsum[ln] : 0;
    int o1 = (64 + ln < nb) ? bsum[64 + ln] : 0;
    int v0 = o0, v1 = o1;
    for (int d = 1; d < 64; d <<= 1) { int t = __shfl_up(v0, d, 64); if (ln >= d) v0 += t; }
    int tot0 = __shfl(v0, 63, 64);
    for (int d = 1; d < 64; d <<= 1) { int t = __shfl_up(v1, d, 64); if (ln >= d) v1 += t; }
    v1 += tot0;
    if (ln < nb) bsum[ln] = v0 - o0;
    if (64 + ln < nb) bsum[64 + ln] = v1 - o1;
    if (ln == 0) row_ptr[N_NODES] = N_EDGES;
}

__global__ void __launch_bounds__(SCB)
deg_scan(const int* __restrict__ deg, const int* __restrict__ bsum,
         int* __restrict__ row_ptr, int* __restrict__ cursor) {
    __shared__ int sd[SCB];
    int tid = threadIdx.x;
    int i = blockIdx.x * SCB + tid;
    int v = (i < N_NODES) ? deg[i] : 0;
    sd[tid] = v;
    __syncthreads();
    for (int off = 1; off < SCB; off <<= 1) {
        int t = (tid >= off) ? sd[tid - off] : 0;
        __syncthreads();
        sd[tid] += t;
        __syncthreads();
    }
    if (i < N_NODES) {
        int ex = sd[tid] - v + bsum[blockIdx.x];
        row_ptr[i] = ex;
        cursor[i] = ex;
    }
}

// XCD-partitioned scatter: blocks with blockIdx%8==p handle dst in [p*PSZ,(p+1)*PSZ).
// All writers of any 64B srcs line then run on one XCD -> line assembled in its L2,
// evicted once (write traffic ~3.2MB instead of 800K x 64B = 51MB).
__global__ void __launch_bounds__(256)
fill_csr_x(const int* __restrict__ src, const int* __restrict__ dst,
           int* __restrict__ cursor, int* __restrict__ srcs, int blocksPerPart) {
    int part = blockIdx.x & (NPART - 1);
    int sub  = blockIdx.x >> 3;
    int lo = part * PSZ, hi = lo + PSZ;
    int stride = blocksPerPart * 256;
    for (int i = sub * 256 + threadIdx.x; i < N_EDGES; i += stride) {
        int d = dst[i];
        if (d >= lo && d < hi) {
            int pos = atomicAdd(&cursor[d], 1);
            srcs[pos] = src[i];
        }
    }
}

// ---------------- MFMA GEMM + fused el/er ----------------
// C[N,128] = A[N,128] @ W[128,128]; block = 32 rows, 4 waves (wave w -> cols w*32..+31).
// EXT=true: A is the external input, decode via dflag; else A is FT-typed workspace.

template<bool EXT, typename AT>
__global__ void __launch_bounds__(256)
gemm_mfma(const void* __restrict__ A, const u16* __restrict__ Wt,
          const void* __restrict__ alw, const void* __restrict__ arw,
          u16* __restrict__ C, float* __restrict__ el, float* __restrict__ er,
          const int* __restrict__ dflag, int nrows) {
    __shared__ __align__(16) char smem[32 * 132 * 4];   // Ct fp32 (16896 B) aliases As bf16 (8704 B)
    u16   (*As)[136] = (u16(*)[136])smem;
    float (*Ct)[132] = (float(*)[132])smem;
    __shared__ u16 alv[128], arv[128];
    const bool isf32 = (*dflag != 0);
    int tid = threadIdx.x;
    if (tid < 128) {
        alv[tid] = f2bf(ldin(alw, tid, isf32));
        arv[tid] = f2bf(ldin(arw, tid, isf32));
    }
    int rowBase = blockIdx.x * 32;
    for (int t = tid; t < 1024; t += 256) {
        int r = t >> 5, q = t & 31;
        int n = rowBase + r;
        float4 v = make_float4(0.f, 0.f, 0.f, 0.f);
        if (n < nrows) {
            if (EXT) v = ldin4(A, n * 32 + q, isf32);
            else     v = ld4f((const AT*)A + (size_t)n * FDIM + q * 4);
        }
        ushort4 u; u.x = f2bf(v.x); u.y = f2bf(v.y); u.z = f2bf(v.z); u.w = f2bf(v.w);
        *(ushort4*)&As[r][q * 4] = u;
    }
    int wv = tid >> 6, ln = tid & 63;
    int ln15 = ln & 15, quad = ln >> 4;
    bf16x8 bfr[2][4];
    #pragma unroll
    for (int c = 0; c < 2; c++)
        #pragma unroll
        for (int kk = 0; kk < 4; kk++)
            bfr[c][kk] = *(const bf16x8*)(Wt + (wv * 32 + c * 16 + ln15) * FDIM + kk * 32 + quad * 8);
    __syncthreads();
    f32x4 acc[2][2] = {};   // [row-tile][col-tile]
    #pragma unroll
    for (int kk = 0; kk < 4; kk++) {
        bf16x8 a0 = *(const bf16x8*)&As[ln15][kk * 32 + quad * 8];
        bf16x8 a1 = *(const bf16x8*)&As[16 + ln15][kk * 32 + quad * 8];
        acc[0][0] = __builtin_amdgcn_mfma_f32_16x16x32_bf16(a0, bfr[0][kk], acc[0][0], 0, 0, 0);
        acc[1][0] = __builtin_amdgcn_mfma_f32_16x16x32_bf16(a1, bfr[0][kk], acc[1][0], 0, 0, 0);
        acc[0][1] = __builtin_amdgcn_mfma_f32_16x16x32_bf16(a0, bfr[1][kk], acc[0][1], 0, 0, 0);
        acc[1][1] = __builtin_amdgcn_mfma_f32_16x16x32_bf16(a1, bfr[1][kk], acc[1][1], 0, 0, 0);
    }
    __syncthreads();   // all As reads done; smem becomes Ct
    #pragma unroll
    for (int r = 0; r < 2; r++)
        #pragma unroll
        for (int c = 0; c < 2; c++)
            #pragma unroll
            for (int p = 0; p < 4; p++)
                Ct[r * 16 + quad * 4 + p][wv * 32 + c * 16 + ln15] = acc[r][c][p];
    __syncthreads();
    // coalesced bf16 C store
    int jc = (tid & 31) * 4, r0 = (tid >> 5) * 4;
    #pragma unroll
    for (int r = 0; r < 4; r++) {
        int n = rowBase + r0 + r;
        if (n < nrows)
            st4(C + (size_t)n * FDIM + jc, *(const float4*)&Ct[r0 + r][jc]);
    }
    // fused el/er
    int row = tid >> 3, head = tid & 7;
    int n2 = rowBase + row;
    if (n2 < nrows) {
        float sl = 0.f, sr = 0.f;
        #pragma unroll
        for (int k = 0; k < HID; k++) {
            float v = Ct[row][head * HID + k];
            sl += v * bf2f(alv[head * HID + k]);
            sr += v * bf2f(arv[head * HID + k]);
        }
        el[n2 * HEADS + head] = sl;
        er[n2 * HEADS + head] = sr;
    }
}

// ---------------- attention aggregation (one wave per node, no-max softmax) ----------------
// Unroll x8 for memory-level parallelism on the random feat-row gathers.

template<typename OT, bool ACT>
__global__ void __launch_bounds__(256)
agg_attn(const u16* __restrict__ feat, const float* __restrict__ el,
         const float* __restrict__ er, const int* __restrict__ row_ptr,
         const int* __restrict__ srcs, OT* __restrict__ out) {
    int wid = (blockIdx.x * 256 + threadIdx.x) >> 6;
    int lane = threadIdx.x & 63;
    if (wid >= N_NODES) return;
    int h  = lane >> 3;          // head 0..7
    int c0 = lane * 2;           // cols 2i, 2i+1
    int beg = row_ptr[wid], end = row_ptr[wid + 1];
    float ern = er[wid * HEADS + h];
    const u16* fb = feat + c0;
    float ss[8] = {}, p0[8] = {}, p1[8] = {};
    int i = beg;
    for (; i + 7 < end; i += 8) {
        int s[8];
        unsigned int u[8];
        float e[8];
        #pragma unroll
        for (int j = 0; j < 8; j++) s[j] = srcs[i + j];
        #pragma unroll
        for (int j = 0; j < 8; j++) u[j] = *(const unsigned int*)(fb + (size_t)s[j] * FDIM);
        #pragma unroll
        for (int j = 0; j < 8; j++) e[j] = el[s[j] * HEADS + h] + ern;
        #pragma unroll
        for (int j = 0; j < 8; j++) {
            float ee = fmaxf(e[j], 0.2f * e[j]);
            float x = __expf(fminf(ee, 80.f));
            ss[j] += x;
            p0[j] = fmaf(x, bf2f((u16)u[j]), p0[j]);
            p1[j] = fmaf(x, bf2f((u16)(u[j] >> 16)), p1[j]);
        }
    }
    for (; i < end; i++) {
        int s0 = srcs[i];
        float e0 = el[s0 * HEADS + h] + ern;
        unsigned int u0 = *(const unsigned int*)(fb + (size_t)s0 * FDIM);
        e0 = fmaxf(e0, 0.2f * e0);
        float x0 = __expf(fminf(e0, 80.f));
        ss[0] += x0;
        p0[0] = fmaf(x0, bf2f((u16)u0), p0[0]);
        p1[0] = fmaf(x0, bf2f((u16)(u0 >> 16)), p1[0]);
    }
    float sst = ((ss[0] + ss[1]) + (ss[2] + ss[3])) + ((ss[4] + ss[5]) + (ss[6] + ss[7]));
    float a0  = ((p0[0] + p0[1]) + (p0[2] + p0[3])) + ((p0[4] + p0[5]) + (p0[6] + p0[7]));
    float a1  = ((p1[0] + p1[1]) + (p1[2] + p1[3])) + ((p1[4] + p1[5]) + (p1[6] + p1[7]));
    float r0 = (end > beg) ? a0 / sst : 0.f;
    float r1 = (end > beg) ? a1 / sst : 0.f;
    if (ACT) {
        r0 = (r0 > 0.f) ? r0 : (__expf(r0) - 1.f);   // ELU
        r1 = (r1 > 0.f) ? r1 : (__expf(r1) - 1.f);
    }
    st2(out + (size_t)wid * FDIM + c0, r0, r1);
}

// ---------------- layer 4 (H=1, D=10): GEMM fused with el/er ----------------

template<typename AT>
__global__ void __launch_bounds__(256)
gemm4(const AT* __restrict__ A, const void* __restrict__ W,
      const void* __restrict__ alw, const void* __restrict__ arw,
      float* __restrict__ out, float* __restrict__ el, float* __restrict__ er,
      const int* __restrict__ dflag) {
    __shared__ float Wl[128][16];
    const bool isf32 = (*dflag != 0);
    for (int t = threadIdx.x; t < 128 * 16; t += 256) {
        int k = t >> 4, c = t & 15;
        Wl[k][c] = (c < NCLS) ? ldin(W, k * NCLS + c, isf32) : 0.f;
    }
    __syncthreads();
    int idx = blockIdx.x * 256 + threadIdx.x;
    int n = idx >> 4, c = idx & 15;
    if (n >= N_NODES) return;
    const AT* a = A + (size_t)n * FDIM;
    float acc = 0.f;
    #pragma unroll
    for (int q = 0; q < 32; q++) {
        float4 v = ld4f(a + q * 4);
        acc += v.x * Wl[q * 4 + 0][c] + v.y * Wl[q * 4 + 1][c] +
               v.z * Wl[q * 4 + 2][c] + v.w * Wl[q * 4 + 3][c];
    }
    if (c < NCLS) out[n * NCLS + c] = acc;
    float alc = (c < NCLS) ? ldin(alw, c, isf32) : 0.f;
    float arc = (c < NCLS) ? ldin(arw, c, isf32) : 0.f;
    float sl = acc * alc, sr = acc * arc;
    #pragma unroll
    for (int off = 8; off >= 1; off >>= 1) {
        sl += __shfl_xor(sl, off, 64);
        sr += __shfl_xor(sr, off, 64);
    }
    if (c == 0) { el[n] = sl; er[n] = sr; }
}

// ---------------- final aggregation: 4 nodes per wave (16 lanes each) ----------------

__global__ void __launch_bounds__(256)
agg4(const float* __restrict__ feat, const float* __restrict__ el,
     const float* __restrict__ er, const int* __restrict__ row_ptr,
     const int* __restrict__ srcs, void* __restrict__ out,
     const int* __restrict__ dflag) {
    const bool isf32 = (*dflag != 0);
    int wid = (blockIdx.x * 256 + threadIdx.x) >> 6;
    int lane = threadIdx.x & 63;
    int g = lane >> 4, t = lane & 15;
    int node = wid * 4 + g;
    bool vn = node < N_NODES;
    int nn = vn ? node : 0;
    int beg = row_ptr[nn];
    int end = vn ? row_ptr[nn + 1] : beg;
    float ern = er[nn];
    int deg = end - beg;
    int mx = deg;
    mx = max(mx, __shfl_xor(mx, 16, 64));
    mx = max(mx, __shfl_xor(mx, 32, 64));
    int tc = (t < NCLS) ? t : 0;
    float ssA = 0.f, ssB = 0.f, aA = 0.f, aB = 0.f;
    int k = 0;
    for (; k + 1 < mx; k += 2) {
        int i0 = beg + k, i1 = i0 + 1;
        bool v0 = i0 < end, v1 = i1 < end;
        int s0 = v0 ? srcs[i0] : 0;
        int s1 = v1 ? srcs[i1] : 0;
        float e0 = el[s0] + ern;
        float e1 = el[s1] + ern;
        float f0 = feat[s0 * NCLS + tc];
        float f1 = feat[s1 * NCLS + tc];
        e0 = fmaxf(e0, 0.2f * e0); e1 = fmaxf(e1, 0.2f * e1);
        float x0 = v0 ? __expf(fminf(e0, 80.f)) : 0.f;
        float x1 = v1 ? __expf(fminf(e1, 80.f)) : 0.f;
        ssA += x0; ssB += x1;
        aA = fmaf(x0, f0, aA);
        aB = fmaf(x1, f1, aB);
    }
    if (k < mx) {
        int i0 = beg + k;
        bool v0 = i0 < end;
        int s0 = v0 ? srcs[i0] : 0;
        float e0 = el[s0] + ern;
        e0 = fmaxf(e0, 0.2f * e0);
        float x0 = v0 ? __expf(fminf(e0, 80.f)) : 0.f;
        ssA += x0;
        aA = fmaf(x0, feat[s0 * NCLS + tc], aA);
    }
    float ss = ssA + ssB, a = aA + aB;
    if (vn && t < NCLS) {
        float r = (deg > 0) ? a / ss : 0.f;
        if (isf32) ((float*)out)[node * NCLS + t] = r;
        else       ((u16*)out)[node * NCLS + t] = f2bf(r);
    }
}

// ---------------- launch ----------------

template<typename FT>
static void run_pipeline(const void* h_in, const int* src, const int* dst,
                         const void* const* W, const void* const* al, const void* const* ar,
                         void* d_out, char* ws, hipStream_t stream) {
    size_t off = 0;
    auto alloc = [&](size_t bytes) {
        void* p = ws + off;
        off = (off + bytes + 255) & ~(size_t)255;
        return p;
    };
    int* dflag   = (int*)alloc(4);
    FT* bufA     = (FT*)alloc((size_t)N_NODES * FDIM * sizeof(FT));   // agg output / GEMM input
    u16* bufB    = (u16*)alloc((size_t)N_NODES * FDIM * sizeof(u16)); // bf16 feat (gather target)
    u16* Wt      = (u16*)alloc(4ull * FDIM * FDIM * sizeof(u16));     // transposed bf16 weights
    float* elb   = (float*)alloc((size_t)N_NODES * HEADS * 4);
    float* erb   = (float*)alloc((size_t)N_NODES * HEADS * 4);
    float* cls   = (float*)alloc((size_t)N_NODES * NCLS * 4);
    int* deg     = (int*)alloc((size_t)N_NODES * 4);
    int* row_ptr = (int*)alloc((size_t)(N_NODES + 1) * 4);
    int* cursor  = (int*)alloc((size_t)N_NODES * 4);
    int* srcs    = (int*)alloc((size_t)N_EDGES * 4);
    int* bsum    = (int*)alloc(256 * 4);

    const int NB = (N_NODES + SCB - 1) / SCB;   // 98 scan blocks

    detect_dtype<<<1, 256, 0, stream>>>((const u16*)W[0], FDIM * FDIM, dflag);
    prep_wt<<<dim3((FDIM * FDIM + 255) / 256, 4), 256, 0, stream>>>(
        W[0], W[1], W[2], W[3], Wt, dflag);

    zero_int<<<(N_NODES + 255) / 256, 256, 0, stream>>>(deg, N_NODES);
    count_deg<<<(N_EDGES + 255) / 256, 256, 0, stream>>>(dst, deg);
    deg_bsum<<<NB, SCB, 0, stream>>>(deg, bsum);
    scan_bsum<<<1, 64, 0, stream>>>(bsum, NB, row_ptr);
    deg_scan<<<NB, SCB, 0, stream>>>(deg, bsum, row_ptr, cursor);
    const int BPP = 64;   // blocks per partition
    fill_csr_x<<<NPART * BPP, 256, 0, stream>>>(src, dst, cursor, srcs, BPP);

    for (int l = 0; l < 4; l++) {
        if (l == 0)
            gemm_mfma<true, FT><<<(N_NODES + 31) / 32, 256, 0, stream>>>(
                h_in, Wt, al[0], ar[0], bufB, elb, erb, dflag, N_NODES);
        else
            gemm_mfma<false, FT><<<(N_NODES + 31) / 32, 256, 0, stream>>>(
                bufA, Wt + l * FDIM * FDIM, al[l], ar[l], bufB, elb, erb, dflag, N_NODES);
        agg_attn<FT, true><<<(N_NODES + 3) / 4, 256, 0, stream>>>(
            bufB, elb, erb, row_ptr, srcs, bufA);
    }
    gemm4<FT><<<(N_NODES * 16 + 255) / 256, 256, 0, stream>>>(
        bufA, W[4], al[4], ar[4], cls, elb, erb, dflag);
    agg4<<<(N_NODES / 16 + 1), 256, 0, stream>>>(cls, elb, erb, row_ptr, srcs, d_out, dflag);
}

extern "C" void kernel_launch(void* const* d_in, const int* in_sizes, int n_in,
                              void* d_out, int out_size, void* d_ws, size_t ws_size,
                              hipStream_t stream) {
    const void* h_in = d_in[0];
    const int* src   = (const int*)d_in[1];
    const int* dst   = (const int*)d_in[2];
    const void *W[5], *al[5], *ar[5];
    for (int l = 0; l < 5; l++) {
        W[l]  = d_in[3 + 3 * l];
        al[l] = d_in[4 + 3 * l];
        ar[l] = d_in[5 + 3 * l];
    }

    const size_t NEED_FP32 = 256
                           + ((size_t)N_NODES * FDIM * 4 + 256)        // bufA fp32
                           + ((size_t)N_NODES * FDIM * 2 + 256)        // bufB bf16
                           + (4ull * FDIM * FDIM * 2 + 256)            // Wt
                           + 2ull * ((size_t)N_NODES * HEADS * 4 + 256)
                           + ((size_t)N_NODES * NCLS * 4 + 256)
                           + 3ull * ((size_t)(N_NODES + 1) * 4 + 256)
                           + ((size_t)N_EDGES * 4 + 256)
                           + (256 * 4 + 256);
    if (ws_size >= NEED_FP32)
        run_pipeline<float>(h_in, src, dst, W, al, ar, d_out, (char*)d_ws, stream);
    else
        run_pipeline<u16>(h_in, src, dst, W, al, ar, d_out, (char*)d_ws, stream);
}

// Round 8
// 473.297 us; speedup vs baseline: 1.0246x; 1.0246x over previous
//
#include <hip/hip_runtime.h>
#include <hip/hip_bf16.h>

#define N_NODES 50000
#define N_EDGES 800000
#define FDIM    128
#define HEADS   8
#define HID     16
#define NCLS    10
#define SCB     512   // scan block size
#define NPART   8     // XCD partitions for the CSR scatter
#define PSZ     6250  // N_NODES / NPART

typedef unsigned short u16;
typedef __attribute__((ext_vector_type(8))) short bf16x8;
typedef __attribute__((ext_vector_type(4))) float f32x4;

__device__ __forceinline__ float bf2f(u16 u) {
    union { unsigned int i; float f; } c; c.i = ((unsigned int)u) << 16; return c.f;
}
__device__ __forceinline__ float bf2f_hi(unsigned int u) {   // high half, no shift needed
    union { unsigned int i; float f; } c; c.i = u & 0xffff0000u; return c.f;
}
__device__ __forceinline__ float bf2f_lo(unsigned int u) {
    union { unsigned int i; float f; } c; c.i = u << 16; return c.f;
}
__device__ __forceinline__ u16 f2bf(float f) {
    union { float f; unsigned int i; } c; c.f = f;
    unsigned int r = c.i + 0x7FFFu + ((c.i >> 16) & 1u);
    return (u16)(r >> 16);
}
__device__ __forceinline__ float4 bf2f4(ushort4 u) {
    return make_float4(bf2f(u.x), bf2f(u.y), bf2f(u.z), bf2f(u.w));
}
__device__ __forceinline__ float4 ld4f(const u16* p)  { return bf2f4(*(const ushort4*)p); }
__device__ __forceinline__ void   st4(u16* p, float4 v) {
    ushort4 u; u.x = f2bf(v.x); u.y = f2bf(v.y); u.z = f2bf(v.z); u.w = f2bf(v.w);
    *(ushort4*)p = u;
}

// external-input decode (dtype resolved at runtime via flag)
__device__ __forceinline__ float ldin(const void* p, int i, bool isf32) {
    return isf32 ? ((const float*)p)[i] : bf2f(((const u16*)p)[i]);
}
__device__ __forceinline__ float4 ldin4(const void* p, int i4, bool isf32) {
    if (isf32) return ((const float4*)p)[i4];
    return bf2f4(((const ushort4*)p)[i4]);
}

// ---------------- dtype detection (W0 scan) ----------------
__global__ void detect_dtype(const u16* __restrict__ w, int n, int* __restrict__ flag) {
    __shared__ int s_huge, s_zero;
    if (threadIdx.x == 0) { s_huge = 0; s_zero = 0; }
    __syncthreads();
    int huge = 0, zero = 0;
    for (int i = threadIdx.x; i < n; i += 256) {
        u16 b = w[i];
        float v = bf2f(b);
        if (fabsf(v) > 1e9f || v != v) huge++;
        if (b == 0) zero++;
    }
    atomicAdd(&s_huge, huge);
    atomicAdd(&s_zero, zero);
    __syncthreads();
    if (threadIdx.x == 0)
        *flag = (s_huge > 0 || s_zero > n / 4) ? 1 : 0;
}

// ---------------- W transpose to bf16 (Wt[n][k]) for MFMA B-frags ----------------
__global__ void prep_wt(const void* __restrict__ W0, const void* __restrict__ W1,
                        const void* __restrict__ W2, const void* __restrict__ W3,
                        u16* __restrict__ Wt, const int* __restrict__ dflag) {
    const bool isf32 = (*dflag != 0);
    int l = blockIdx.y;
    const void* W = (l == 0) ? W0 : (l == 1) ? W1 : (l == 2) ? W2 : W3;
    int i = blockIdx.x * 256 + threadIdx.x;
    if (i >= FDIM * FDIM) return;
    int n = i >> 7, k = i & 127;
    Wt[l * FDIM * FDIM + n * FDIM + k] = f2bf(ldin(W, k * FDIM + n, isf32));
}

// ---------------- CSR build ----------------

__global__ void zero_int(int* p, int n) {
    int i = blockIdx.x * blockDim.x + threadIdx.x;
    if (i < n) p[i] = 0;
}

__global__ void count_deg(const int* __restrict__ dst, int* __restrict__ deg) {
    int i = blockIdx.x * blockDim.x + threadIdx.x;
    if (i < N_EDGES) atomicAdd(&deg[__builtin_nontemporal_load(&dst[i])], 1);
}

__global__ void __launch_bounds__(SCB)
deg_bsum(const int* __restrict__ deg, int* __restrict__ bsum) {
    int i = blockIdx.x * SCB + threadIdx.x;
    int v = (i < N_NODES) ? deg[i] : 0;
    for (int off = 32; off; off >>= 1) v += __shfl_down(v, off, 64);
    __shared__ int wsum[SCB / 64];
    int wv = threadIdx.x >> 6, ln = threadIdx.x & 63;
    if (ln == 0) wsum[wv] = v;
    __syncthreads();
    if (threadIdx.x == 0) {
        int s = 0;
        #pragma unroll
        for (int k = 0; k < SCB / 64; k++) s += wsum[k];
        bsum[blockIdx.x] = s;
    }
}

__global__ void scan_bsum(int* __restrict__ bsum, int nb, int* __restrict__ row_ptr) {
    int ln = threadIdx.x;  // 64 threads, nb <= 128
    int o0 = (ln < nb) ? bsum[ln] : 0;
    int o1 = (64 + ln < nb) ? bsum[64 + ln] : 0;
    int v0 = o0, v1 = o1;
    for (int d = 1; d < 64; d <<= 1) { int t = __shfl_up(v0, d, 64); if (ln >= d) v0 += t; }
    int tot0 = __shfl(v0, 63, 64);
    for (int d = 1; d < 64; d <<= 1) { int t = __shfl_up(v1, d, 64); if (ln >= d) v1 += t; }
    v1 += tot0;
    if (ln < nb) bsum[ln] = v0 - o0;
    if (64 + ln < nb) bsum[64 + ln] = v1 - o1;
    if (ln == 0) row_ptr[N_NODES] = N_EDGES;
}

__global__ void __launch_bounds__(SCB)
deg_scan(const int* __restrict__ deg, const int* __restrict__ bsum,
         int* __restrict__ row_ptr, int* __restrict__ cursor) {
    __shared__ int sd[SCB];
    int tid = threadIdx.x;
    int i = blockIdx.x * SCB + tid;
    int v = (i < N_NODES) ? deg[i] : 0;
    sd[tid] = v;
    __syncthreads();
    for (int off = 1; off < SCB; off <<= 1) {
        int t = (tid >= off) ? sd[tid - off] : 0;
        __syncthreads();
        sd[tid] += t;
        __syncthreads();
    }
    if (i < N_NODES) {
        int ex = sd[tid] - v + bsum[blockIdx.x];
        row_ptr[i] = ex;
        cursor[i] = ex;
    }
}

// XCD-partitioned scatter; nt loads on the src/dst streams so they don't evict
// the partially-assembled srcs lines from L2 before they fill.
__global__ void __launch_bounds__(256)
fill_csr_x(const int* __restrict__ src, const int* __restrict__ dst,
           int* __restrict__ cursor, int* __restrict__ srcs, int blocksPerPart) {
    int part = blockIdx.x & (NPART - 1);
    int sub  = blockIdx.x >> 3;
    int lo = part * PSZ, hi = lo + PSZ;
    int stride = blocksPerPart * 256;
    for (int i = sub * 256 + threadIdx.x; i < N_EDGES; i += stride) {
        int d = __builtin_nontemporal_load(&dst[i]);
        if (d >= lo && d < hi) {
            int pos = atomicAdd(&cursor[d], 1);
            srcs[pos] = __builtin_nontemporal_load(&src[i]);
        }
    }
}

// ---------------- MFMA GEMM + fused el/er ----------------
// C[N,128] = A[N,128] @ W[128,128]; block = 32 rows, 4 waves (wave w -> cols w*32..+31).
// EXT=true: A is the external input (decode via dflag); else A is bf16 workspace.

template<bool EXT>
__global__ void __launch_bounds__(256)
gemm_mfma(const void* __restrict__ A, const u16* __restrict__ Wt,
          const void* __restrict__ alw, const void* __restrict__ arw,
          u16* __restrict__ C, float* __restrict__ el, float* __restrict__ er,
          const int* __restrict__ dflag, int nrows) {
    __shared__ __align__(16) char smem[32 * 132 * 4];   // Ct fp32 (16896 B) aliases As bf16 (8704 B)
    u16   (*As)[136] = (u16(*)[136])smem;
    float (*Ct)[132] = (float(*)[132])smem;
    __shared__ u16 alv[128], arv[128];
    const bool isf32 = (*dflag != 0);
    int tid = threadIdx.x;
    if (tid < 128) {
        alv[tid] = f2bf(ldin(alw, tid, isf32));
        arv[tid] = f2bf(ldin(arw, tid, isf32));
    }
    int rowBase = blockIdx.x * 32;
    for (int t = tid; t < 1024; t += 256) {
        int r = t >> 5, q = t & 31;
        int n = rowBase + r;
        if (EXT) {
            float4 v = make_float4(0.f, 0.f, 0.f, 0.f);
            if (n < nrows) v = ldin4(A, n * 32 + q, isf32);
            ushort4 u; u.x = f2bf(v.x); u.y = f2bf(v.y); u.z = f2bf(v.z); u.w = f2bf(v.w);
            *(ushort4*)&As[r][q * 4] = u;
        } else {
            ushort4 u = make_ushort4(0, 0, 0, 0);
            if (n < nrows) u = *(const ushort4*)((const u16*)A + (size_t)n * FDIM + q * 4);
            *(ushort4*)&As[r][q * 4] = u;
        }
    }
    int wv = tid >> 6, ln = tid & 63;
    int ln15 = ln & 15, quad = ln >> 4;
    bf16x8 bfr[2][4];
    #pragma unroll
    for (int c = 0; c < 2; c++)
        #pragma unroll
        for (int kk = 0; kk < 4; kk++)
            bfr[c][kk] = *(const bf16x8*)(Wt + (wv * 32 + c * 16 + ln15) * FDIM + kk * 32 + quad * 8);
    __syncthreads();
    f32x4 acc[2][2] = {};   // [row-tile][col-tile]
    #pragma unroll
    for (int kk = 0; kk < 4; kk++) {
        bf16x8 a0 = *(const bf16x8*)&As[ln15][kk * 32 + quad * 8];
        bf16x8 a1 = *(const bf16x8*)&As[16 + ln15][kk * 32 + quad * 8];
        acc[0][0] = __builtin_amdgcn_mfma_f32_16x16x32_bf16(a0, bfr[0][kk], acc[0][0], 0, 0, 0);
        acc[1][0] = __builtin_amdgcn_mfma_f32_16x16x32_bf16(a1, bfr[0][kk], acc[1][0], 0, 0, 0);
        acc[0][1] = __builtin_amdgcn_mfma_f32_16x16x32_bf16(a0, bfr[1][kk], acc[0][1], 0, 0, 0);
        acc[1][1] = __builtin_amdgcn_mfma_f32_16x16x32_bf16(a1, bfr[1][kk], acc[1][1], 0, 0, 0);
    }
    __syncthreads();   // all As reads done; smem becomes Ct
    #pragma unroll
    for (int r = 0; r < 2; r++)
        #pragma unroll
        for (int c = 0; c < 2; c++)
            #pragma unroll
            for (int p = 0; p < 4; p++)
                Ct[r * 16 + quad * 4 + p][wv * 32 + c * 16 + ln15] = acc[r][c][p];
    __syncthreads();
    // coalesced bf16 C store
    int jc = (tid & 31) * 4, r0 = (tid >> 5) * 4;
    #pragma unroll
    for (int r = 0; r < 4; r++) {
        int n = rowBase + r0 + r;
        if (n < nrows)
            st4(C + (size_t)n * FDIM + jc, *(const float4*)&Ct[r0 + r][jc]);
    }
    // fused el/er
    int row = tid >> 3, head = tid & 7;
    int n2 = rowBase + row;
    if (n2 < nrows) {
        float sl = 0.f, sr = 0.f;
        #pragma unroll
        for (int k = 0; k < HID; k++) {
            float v = Ct[row][head * HID + k];
            sl += v * bf2f(alv[head * HID + k]);
            sr += v * bf2f(arv[head * HID + k]);
        }
        el[n2 * HEADS + head] = sl;
        er[n2 * HEADS + head] = sr;
    }
}

// ---------------- attention aggregation: 1 node/wave, 4 edge slots x 16 lanes ----------------
// lane = (g=lane>>4: edge slot, q=lane&15: 16B column quarter). Each lane loads uint4
// (8 bf16 cols) of its slot's feat row; head h=q>>1; tail edges predicated (x=0).
// Cross-slot reduction via shfl_xor(16/32) once per node.

template<bool ACT>
__global__ void __launch_bounds__(256)
agg_attn(const u16* __restrict__ feat, const float* __restrict__ el,
         const float* __restrict__ er, const int* __restrict__ row_ptr,
         const int* __restrict__ srcs, u16* __restrict__ out) {
    int wid = (blockIdx.x * 256 + threadIdx.x) >> 6;
    int lane = threadIdx.x & 63;
    if (wid >= N_NODES) return;
    int g = lane >> 4;           // edge slot 0..3
    int q = lane & 15;           // column quarter (cols q*8 .. q*8+7)
    int h = q >> 1;              // head 0..7
    int beg = row_ptr[wid], end = row_ptr[wid + 1];
    float ern = er[wid * HEADS + h];
    float ss = 0.f;
    float acc[8] = {};
    for (int i = beg; i < end; i += 4) {
        int idx = i + g;
        bool v = idx < end;
        int s = srcs[v ? idx : beg];
        float e = el[s * HEADS + h] + ern;
        e = fmaxf(e, 0.2f * e);
        float x = v ? __expf(fminf(e, 80.f)) : 0.f;
        uint4 u = *(const uint4*)(feat + (size_t)s * FDIM + q * 8);
        ss += x;
        acc[0] = fmaf(x, bf2f_lo(u.x), acc[0]); acc[1] = fmaf(x, bf2f_hi(u.x), acc[1]);
        acc[2] = fmaf(x, bf2f_lo(u.y), acc[2]); acc[3] = fmaf(x, bf2f_hi(u.y), acc[3]);
        acc[4] = fmaf(x, bf2f_lo(u.z), acc[4]); acc[5] = fmaf(x, bf2f_hi(u.z), acc[5]);
        acc[6] = fmaf(x, bf2f_lo(u.w), acc[6]); acc[7] = fmaf(x, bf2f_hi(u.w), acc[7]);
    }
    // reduce the 4 slots (lanes q, q+16, q+32, q+48)
    ss += __shfl_xor(ss, 16, 64);
    ss += __shfl_xor(ss, 32, 64);
    #pragma unroll
    for (int k = 0; k < 8; k++) {
        acc[k] += __shfl_xor(acc[k], 16, 64);
        acc[k] += __shfl_xor(acc[k], 32, 64);
    }
    if (g == 0) {
        float inv = (end > beg) ? 1.f / ss : 0.f;
        float r[8];
        #pragma unroll
        for (int k = 0; k < 8; k++) {
            float t = acc[k] * inv;
            if (ACT) t = (t > 0.f) ? t : (__expf(t) - 1.f);   // ELU
            r[k] = t;
        }
        uint4 o;
        o.x = (unsigned int)f2bf(r[0]) | ((unsigned int)f2bf(r[1]) << 16);
        o.y = (unsigned int)f2bf(r[2]) | ((unsigned int)f2bf(r[3]) << 16);
        o.z = (unsigned int)f2bf(r[4]) | ((unsigned int)f2bf(r[5]) << 16);
        o.w = (unsigned int)f2bf(r[6]) | ((unsigned int)f2bf(r[7]) << 16);
        *(uint4*)(out + (size_t)wid * FDIM + q * 8) = o;
    }
}

// ---------------- layer 4 (H=1, D=10): GEMM fused with el/er ----------------

__global__ void __launch_bounds__(256)
gemm4(const u16* __restrict__ A, const void* __restrict__ W,
      const void* __restrict__ alw, const void* __restrict__ arw,
      float* __restrict__ out, float* __restrict__ el, float* __restrict__ er,
      const int* __restrict__ dflag) {
    __shared__ float Wl[128][16];
    const bool isf32 = (*dflag != 0);
    for (int t = threadIdx.x; t < 128 * 16; t += 256) {
        int k = t >> 4, c = t & 15;
        Wl[k][c] = (c < NCLS) ? ldin(W, k * NCLS + c, isf32) : 0.f;
    }
    __syncthreads();
    int idx = blockIdx.x * 256 + threadIdx.x;
    int n = idx >> 4, c = idx & 15;
    if (n >= N_NODES) return;
    const u16* a = A + (size_t)n * FDIM;
    float acc = 0.f;
    #pragma unroll
    for (int q = 0; q < 32; q++) {
        float4 v = ld4f(a + q * 4);
        acc += v.x * Wl[q * 4 + 0][c] + v.y * Wl[q * 4 + 1][c] +
               v.z * Wl[q * 4 + 2][c] + v.w * Wl[q * 4 + 3][c];
    }
    if (c < NCLS) out[n * NCLS + c] = acc;
    float alc = (c < NCLS) ? ldin(alw, c, isf32) : 0.f;
    float arc = (c < NCLS) ? ldin(arw, c, isf32) : 0.f;
    float sl = acc * alc, sr = acc * arc;
    #pragma unroll
    for (int off = 8; off >= 1; off >>= 1) {
        sl += __shfl_xor(sl, off, 64);
        sr += __shfl_xor(sr, off, 64);
    }
    if (c == 0) { el[n] = sl; er[n] = sr; }
}

// ---------------- final aggregation: 4 nodes per wave (16 lanes each) ----------------

__global__ void __launch_bounds__(256)
agg4(const float* __restrict__ feat, const float* __restrict__ el,
     const float* __restrict__ er, const int* __restrict__ row_ptr,
     const int* __restrict__ srcs, void* __restrict__ out,
     const int* __restrict__ dflag) {
    const bool isf32 = (*dflag != 0);
    int wid = (blockIdx.x * 256 + threadIdx.x) >> 6;
    int lane = threadIdx.x & 63;
    int g = lane >> 4, t = lane & 15;
    int node = wid * 4 + g;
    bool vn = node < N_NODES;
    int nn = vn ? node : 0;
    int beg = row_ptr[nn];
    int end = vn ? row_ptr[nn + 1] : beg;
    float ern = er[nn];
    int deg = end - beg;
    int mx = deg;
    mx = max(mx, __shfl_xor(mx, 16, 64));
    mx = max(mx, __shfl_xor(mx, 32, 64));
    int tc = (t < NCLS) ? t : 0;
    float ssA = 0.f, ssB = 0.f, aA = 0.f, aB = 0.f;
    int k = 0;
    for (; k + 1 < mx; k += 2) {
        int i0 = beg + k, i1 = i0 + 1;
        bool v0 = i0 < end, v1 = i1 < end;
        int s0 = v0 ? srcs[i0] : 0;
        int s1 = v1 ? srcs[i1] : 0;
        float e0 = el[s0] + ern;
        float e1 = el[s1] + ern;
        float f0 = feat[s0 * NCLS + tc];
        float f1 = feat[s1 * NCLS + tc];
        e0 = fmaxf(e0, 0.2f * e0); e1 = fmaxf(e1, 0.2f * e1);
        float x0 = v0 ? __expf(fminf(e0, 80.f)) : 0.f;
        float x1 = v1 ? __expf(fminf(e1, 80.f)) : 0.f;
        ssA += x0; ssB += x1;
        aA = fmaf(x0, f0, aA);
        aB = fmaf(x1, f1, aB);
    }
    if (k < mx) {
        int i0 = beg + k;
        bool v0 = i0 < end;
        int s0 = v0 ? srcs[i0] : 0;
        float e0 = el[s0] + ern;
        e0 = fmaxf(e0, 0.2f * e0);
        float x0 = v0 ? __expf(fminf(e0, 80.f)) : 0.f;
        ssA += x0;
        aA = fmaf(x0, feat[s0 * NCLS + tc], aA);
    }
    float ss = ssA + ssB, a = aA + aB;
    if (vn && t < NCLS) {
        float r = (deg > 0) ? a / ss : 0.f;
        if (isf32) ((float*)out)[node * NCLS + t] = r;
        else       ((u16*)out)[node * NCLS + t] = f2bf(r);
    }
}

// ---------------- launch ----------------

extern "C" void kernel_launch(void* const* d_in, const int* in_sizes, int n_in,
                              void* d_out, int out_size, void* d_ws, size_t ws_size,
                              hipStream_t stream) {
    const void* h_in = d_in[0];
    const int* src   = (const int*)d_in[1];
    const int* dst   = (const int*)d_in[2];
    const void *W[5], *al[5], *ar[5];
    for (int l = 0; l < 5; l++) {
        W[l]  = d_in[3 + 3 * l];
        al[l] = d_in[4 + 3 * l];
        ar[l] = d_in[5 + 3 * l];
    }

    char* ws = (char*)d_ws;
    size_t off = 0;
    auto alloc = [&](size_t bytes) {
        void* p = ws + off;
        off = (off + bytes + 255) & ~(size_t)255;
        return p;
    };
    int* dflag   = (int*)alloc(4);
    u16* bufA    = (u16*)alloc((size_t)N_NODES * FDIM * sizeof(u16)); // agg output / GEMM input (bf16)
    u16* bufB    = (u16*)alloc((size_t)N_NODES * FDIM * sizeof(u16)); // post-GEMM feat (gather target)
    u16* Wt      = (u16*)alloc(4ull * FDIM * FDIM * sizeof(u16));     // transposed bf16 weights
    float* elb   = (float*)alloc((size_t)N_NODES * HEADS * 4);
    float* erb   = (float*)alloc((size_t)N_NODES * HEADS * 4);
    float* cls   = (float*)alloc((size_t)N_NODES * NCLS * 4);
    int* deg     = (int*)alloc((size_t)N_NODES * 4);
    int* row_ptr = (int*)alloc((size_t)(N_NODES + 1) * 4);
    int* cursor  = (int*)alloc((size_t)N_NODES * 4);
    int* srcs    = (int*)alloc((size_t)N_EDGES * 4);
    int* bsum    = (int*)alloc(256 * 4);

    const int NB = (N_NODES + SCB - 1) / SCB;   // 98 scan blocks

    detect_dtype<<<1, 256, 0, stream>>>((const u16*)W[0], FDIM * FDIM, dflag);
    prep_wt<<<dim3((FDIM * FDIM + 255) / 256, 4), 256, 0, stream>>>(
        W[0], W[1], W[2], W[3], Wt, dflag);

    zero_int<<<(N_NODES + 255) / 256, 256, 0, stream>>>(deg, N_NODES);
    count_deg<<<(N_EDGES + 255) / 256, 256, 0, stream>>>(dst, deg);
    deg_bsum<<<NB, SCB, 0, stream>>>(deg, bsum);
    scan_bsum<<<1, 64, 0, stream>>>(bsum, NB, row_ptr);
    deg_scan<<<NB, SCB, 0, stream>>>(deg, bsum, row_ptr, cursor);
    const int BPP = 64;   // blocks per partition
    fill_csr_x<<<NPART * BPP, 256, 0, stream>>>(src, dst, cursor, srcs, BPP);

    for (int l = 0; l < 4; l++) {
        if (l == 0)
            gemm_mfma<true><<<(N_NODES + 31) / 32, 256, 0, stream>>>(
                h_in, Wt, al[0], ar[0], bufB, elb, erb, dflag, N_NODES);
        else
            gemm_mfma<false><<<(N_NODES + 31) / 32, 256, 0, stream>>>(
                bufA, Wt + l * FDIM * FDIM, al[l], ar[l], bufB, elb, erb, dflag, N_NODES);
        agg_attn<true><<<(N_NODES + 3) / 4, 256, 0, stream>>>(
            bufB, elb, erb, row_ptr, srcs, bufA);
    }
    gemm4<<<(N_NODES * 16 + 255) / 256, 256, 0, stream>>>(
        bufA, W[4], al[4], ar[4], cls, elb, erb, dflag);
    agg4<<<(N_NODES / 16 + 1), 256, 0, stream>>>(cls, elb, erb, row_ptr, srcs, d_out, dflag);
}

// Round 9
// 449.271 us; speedup vs baseline: 1.0794x; 1.0535x over previous
//
#include <hip/hip_runtime.h>
#include <hip/hip_bf16.h>

#define N_NODES 50000
#define N_EDGES 800000
#define FDIM    128
#define HEADS   8
#define HID     16
#define NCLS    10
#define CLSP    16    // padded cls row (64B aligned)
#define SCB     512   // scan block size
#define NPART   8     // XCD partitions for the CSR scatter
#define PSZ     6250  // N_NODES / NPART

typedef unsigned short u16;
typedef __attribute__((ext_vector_type(8))) short bf16x8;
typedef __attribute__((ext_vector_type(4))) float f32x4;

__device__ __forceinline__ float bf2f(u16 u) {
    union { unsigned int i; float f; } c; c.i = ((unsigned int)u) << 16; return c.f;
}
__device__ __forceinline__ float bf2f_hi(unsigned int u) {
    union { unsigned int i; float f; } c; c.i = u & 0xffff0000u; return c.f;
}
__device__ __forceinline__ float bf2f_lo(unsigned int u) {
    union { unsigned int i; float f; } c; c.i = u << 16; return c.f;
}
__device__ __forceinline__ u16 f2bf(float f) {
    union { float f; unsigned int i; } c; c.f = f;
    unsigned int r = c.i + 0x7FFFu + ((c.i >> 16) & 1u);
    return (u16)(r >> 16);
}
__device__ __forceinline__ float4 bf2f4(ushort4 u) {
    return make_float4(bf2f(u.x), bf2f(u.y), bf2f(u.z), bf2f(u.w));
}
__device__ __forceinline__ float4 ld4f(const u16* p)  { return bf2f4(*(const ushort4*)p); }
__device__ __forceinline__ void   st4(u16* p, float4 v) {
    ushort4 u; u.x = f2bf(v.x); u.y = f2bf(v.y); u.z = f2bf(v.z); u.w = f2bf(v.w);
    *(ushort4*)p = u;
}

// external-input decode (dtype resolved at runtime via flag)
__device__ __forceinline__ float ldin(const void* p, int i, bool isf32) {
    return isf32 ? ((const float*)p)[i] : bf2f(((const u16*)p)[i]);
}
__device__ __forceinline__ float4 ldin4(const void* p, int i4, bool isf32) {
    if (isf32) return ((const float4*)p)[i4];
    return bf2f4(((const ushort4*)p)[i4]);
}

// ---------------- dtype detection (W0 scan) ----------------
__global__ void detect_dtype(const u16* __restrict__ w, int n, int* __restrict__ flag) {
    __shared__ int s_huge, s_zero;
    if (threadIdx.x == 0) { s_huge = 0; s_zero = 0; }
    __syncthreads();
    int huge = 0, zero = 0;
    for (int i = threadIdx.x; i < n; i += 256) {
        u16 b = w[i];
        float v = bf2f(b);
        if (fabsf(v) > 1e9f || v != v) huge++;
        if (b == 0) zero++;
    }
    atomicAdd(&s_huge, huge);
    atomicAdd(&s_zero, zero);
    __syncthreads();
    if (threadIdx.x == 0)
        *flag = (s_huge > 0 || s_zero > n / 4) ? 1 : 0;
}

// ---------------- W transpose to bf16 (Wt[n][k]) for MFMA B-frags ----------------
__global__ void prep_wt(const void* __restrict__ W0, const void* __restrict__ W1,
                        const void* __restrict__ W2, const void* __restrict__ W3,
                        u16* __restrict__ Wt, const int* __restrict__ dflag) {
    const bool isf32 = (*dflag != 0);
    int l = blockIdx.y;
    const void* W = (l == 0) ? W0 : (l == 1) ? W1 : (l == 2) ? W2 : W3;
    int i = blockIdx.x * 256 + threadIdx.x;
    if (i >= FDIM * FDIM) return;
    int n = i >> 7, k = i & 127;
    Wt[l * FDIM * FDIM + n * FDIM + k] = f2bf(ldin(W, k * FDIM + n, isf32));
}

// ---------------- CSR build ----------------

__global__ void zero_int(int* p, int n) {
    int i = blockIdx.x * blockDim.x + threadIdx.x;
    if (i < n) p[i] = 0;
}

__global__ void count_deg(const int* __restrict__ dst, int* __restrict__ deg) {
    int i = blockIdx.x * blockDim.x + threadIdx.x;
    if (i < N_EDGES) atomicAdd(&deg[__builtin_nontemporal_load(&dst[i])], 1);
}

__global__ void __launch_bounds__(SCB)
deg_bsum(const int* __restrict__ deg, int* __restrict__ bsum) {
    int i = blockIdx.x * SCB + threadIdx.x;
    int v = (i < N_NODES) ? deg[i] : 0;
    for (int off = 32; off; off >>= 1) v += __shfl_down(v, off, 64);
    __shared__ int wsum[SCB / 64];
    int wv = threadIdx.x >> 6, ln = threadIdx.x & 63;
    if (ln == 0) wsum[wv] = v;
    __syncthreads();
    if (threadIdx.x == 0) {
        int s = 0;
        #pragma unroll
        for (int k = 0; k < SCB / 64; k++) s += wsum[k];
        bsum[blockIdx.x] = s;
    }
}

__global__ void scan_bsum(int* __restrict__ bsum, int nb, int* __restrict__ row_ptr) {
    int ln = threadIdx.x;  // 64 threads, nb <= 128
    int o0 = (ln < nb) ? bsum[ln] : 0;
    int o1 = (64 + ln < nb) ? bsum[64 + ln] : 0;
    int v0 = o0, v1 = o1;
    for (int d = 1; d < 64; d <<= 1) { int t = __shfl_up(v0, d, 64); if (ln >= d) v0 += t; }
    int tot0 = __shfl(v0, 63, 64);
    for (int d = 1; d < 64; d <<= 1) { int t = __shfl_up(v1, d, 64); if (ln >= d) v1 += t; }
    v1 += tot0;
    if (ln < nb) bsum[ln] = v0 - o0;
    if (64 + ln < nb) bsum[64 + ln] = v1 - o1;
    if (ln == 0) row_ptr[N_NODES] = N_EDGES;
}

__global__ void __launch_bounds__(SCB)
deg_scan(const int* __restrict__ deg, const int* __restrict__ bsum,
         int* __restrict__ row_ptr, int* __restrict__ cursor) {
    __shared__ int sd[SCB];
    int tid = threadIdx.x;
    int i = blockIdx.x * SCB + tid;
    int v = (i < N_NODES) ? deg[i] : 0;
    sd[tid] = v;
    __syncthreads();
    for (int off = 1; off < SCB; off <<= 1) {
        int t = (tid >= off) ? sd[tid - off] : 0;
        __syncthreads();
        sd[tid] += t;
        __syncthreads();
    }
    if (i < N_NODES) {
        int ex = sd[tid] - v + bsum[blockIdx.x];
        row_ptr[i] = ex;
        cursor[i] = ex;
    }
}

// XCD-partitioned scatter into u16 srcs (node ids < 65536).
__global__ void __launch_bounds__(256)
fill_csr_x(const int* __restrict__ src, const int* __restrict__ dst,
           int* __restrict__ cursor, u16* __restrict__ srcs, int blocksPerPart) {
    int part = blockIdx.x & (NPART - 1);
    int sub  = blockIdx.x >> 3;
    int lo = part * PSZ, hi = lo + PSZ;
    int stride = blocksPerPart * 256;
    for (int i = sub * 256 + threadIdx.x; i < N_EDGES; i += stride) {
        int d = __builtin_nontemporal_load(&dst[i]);
        if (d >= lo && d < hi) {
            int pos = atomicAdd(&cursor[d], 1);
            srcs[pos] = (u16)__builtin_nontemporal_load(&src[i]);
        }
    }
}

// ---------------- MFMA GEMM + fused el/er ----------------
// C[N,128] = A[N,128] @ W[128,128]; block = 32 rows, 4 waves (wave w -> cols w*32..+31).
// EXT=true: A is the external input (decode via dflag); else A is bf16 workspace.

template<bool EXT>
__global__ void __launch_bounds__(256)
gemm_mfma(const void* __restrict__ A, const u16* __restrict__ Wt,
          const void* __restrict__ alw, const void* __restrict__ arw,
          u16* __restrict__ C, float* __restrict__ el, float* __restrict__ er,
          const int* __restrict__ dflag, int nrows) {
    __shared__ __align__(16) char smem[32 * 132 * 4];   // Ct fp32 (16896 B) aliases As bf16 (8704 B)
    u16   (*As)[136] = (u16(*)[136])smem;
    float (*Ct)[132] = (float(*)[132])smem;
    __shared__ u16 alv[128], arv[128];
    const bool isf32 = (*dflag != 0);
    int tid = threadIdx.x;
    if (tid < 128) {
        alv[tid] = f2bf(ldin(alw, tid, isf32));
        arv[tid] = f2bf(ldin(arw, tid, isf32));
    }
    int rowBase = blockIdx.x * 32;
    for (int t = tid; t < 1024; t += 256) {
        int r = t >> 5, q = t & 31;
        int n = rowBase + r;
        if (EXT) {
            float4 v = make_float4(0.f, 0.f, 0.f, 0.f);
            if (n < nrows) v = ldin4(A, n * 32 + q, isf32);
            ushort4 u; u.x = f2bf(v.x); u.y = f2bf(v.y); u.z = f2bf(v.z); u.w = f2bf(v.w);
            *(ushort4*)&As[r][q * 4] = u;
        } else {
            ushort4 u = make_ushort4(0, 0, 0, 0);
            if (n < nrows) u = *(const ushort4*)((const u16*)A + (size_t)n * FDIM + q * 4);
            *(ushort4*)&As[r][q * 4] = u;
        }
    }
    int wv = tid >> 6, ln = tid & 63;
    int ln15 = ln & 15, quad = ln >> 4;
    bf16x8 bfr[2][4];
    #pragma unroll
    for (int c = 0; c < 2; c++)
        #pragma unroll
        for (int kk = 0; kk < 4; kk++)
            bfr[c][kk] = *(const bf16x8*)(Wt + (wv * 32 + c * 16 + ln15) * FDIM + kk * 32 + quad * 8);
    __syncthreads();
    f32x4 acc[2][2] = {};   // [row-tile][col-tile]
    #pragma unroll
    for (int kk = 0; kk < 4; kk++) {
        bf16x8 a0 = *(const bf16x8*)&As[ln15][kk * 32 + quad * 8];
        bf16x8 a1 = *(const bf16x8*)&As[16 + ln15][kk * 32 + quad * 8];
        acc[0][0] = __builtin_amdgcn_mfma_f32_16x16x32_bf16(a0, bfr[0][kk], acc[0][0], 0, 0, 0);
        acc[1][0] = __builtin_amdgcn_mfma_f32_16x16x32_bf16(a1, bfr[0][kk], acc[1][0], 0, 0, 0);
        acc[0][1] = __builtin_amdgcn_mfma_f32_16x16x32_bf16(a0, bfr[1][kk], acc[0][1], 0, 0, 0);
        acc[1][1] = __builtin_amdgcn_mfma_f32_16x16x32_bf16(a1, bfr[1][kk], acc[1][1], 0, 0, 0);
    }
    __syncthreads();   // all As reads done; smem becomes Ct
    #pragma unroll
    for (int r = 0; r < 2; r++)
        #pragma unroll
        for (int c = 0; c < 2; c++)
            #pragma unroll
            for (int p = 0; p < 4; p++)
                Ct[r * 16 + quad * 4 + p][wv * 32 + c * 16 + ln15] = acc[r][c][p];
    __syncthreads();
    // coalesced bf16 C store
    int jc = (tid & 31) * 4, r0 = (tid >> 5) * 4;
    #pragma unroll
    for (int r = 0; r < 4; r++) {
        int n = rowBase + r0 + r;
        if (n < nrows)
            st4(C + (size_t)n * FDIM + jc, *(const float4*)&Ct[r0 + r][jc]);
    }
    // fused el/er
    int row = tid >> 3, head = tid & 7;
    int n2 = rowBase + row;
    if (n2 < nrows) {
        float sl = 0.f, sr = 0.f;
        #pragma unroll
        for (int k = 0; k < HID; k++) {
            float v = Ct[row][head * HID + k];
            sl += v * bf2f(alv[head * HID + k]);
            sr += v * bf2f(arv[head * HID + k]);
        }
        el[n2 * HEADS + head] = sl;
        er[n2 * HEADS + head] = sr;
    }
}

// ---------------- attention aggregation: 1 node/wave, 4 edge slots x 16 lanes ----------------

template<bool ACT>
__global__ void __launch_bounds__(256)
agg_attn(const u16* __restrict__ feat, const float* __restrict__ el,
         const float* __restrict__ er, const int* __restrict__ row_ptr,
         const u16* __restrict__ srcs, u16* __restrict__ out) {
    int wid = (blockIdx.x * 256 + threadIdx.x) >> 6;
    int lane = threadIdx.x & 63;
    if (wid >= N_NODES) return;
    int g = lane >> 4;           // edge slot 0..3
    int q = lane & 15;           // column quarter (cols q*8 .. q*8+7)
    int h = q >> 1;              // head 0..7
    int beg = row_ptr[wid], end = row_ptr[wid + 1];
    float ern = er[wid * HEADS + h];
    float ss = 0.f;
    float acc[8] = {};
    for (int i = beg; i < end; i += 4) {
        int idx = i + g;
        bool v = idx < end;
        int s = srcs[v ? idx : beg];
        float e = el[s * HEADS + h] + ern;
        e = fmaxf(e, 0.2f * e);
        float x = v ? __expf(fminf(e, 80.f)) : 0.f;
        uint4 u = *(const uint4*)(feat + (size_t)s * FDIM + q * 8);
        ss += x;
        acc[0] = fmaf(x, bf2f_lo(u.x), acc[0]); acc[1] = fmaf(x, bf2f_hi(u.x), acc[1]);
        acc[2] = fmaf(x, bf2f_lo(u.y), acc[2]); acc[3] = fmaf(x, bf2f_hi(u.y), acc[3]);
        acc[4] = fmaf(x, bf2f_lo(u.z), acc[4]); acc[5] = fmaf(x, bf2f_hi(u.z), acc[5]);
        acc[6] = fmaf(x, bf2f_lo(u.w), acc[6]); acc[7] = fmaf(x, bf2f_hi(u.w), acc[7]);
    }
    ss += __shfl_xor(ss, 16, 64);
    ss += __shfl_xor(ss, 32, 64);
    #pragma unroll
    for (int k = 0; k < 8; k++) {
        acc[k] += __shfl_xor(acc[k], 16, 64);
        acc[k] += __shfl_xor(acc[k], 32, 64);
    }
    if (g == 0) {
        float inv = (end > beg) ? 1.f / ss : 0.f;
        float r[8];
        #pragma unroll
        for (int k = 0; k < 8; k++) {
            float t = acc[k] * inv;
            if (ACT) t = (t > 0.f) ? t : (__expf(t) - 1.f);   // ELU
            r[k] = t;
        }
        uint4 o;
        o.x = (unsigned int)f2bf(r[0]) | ((unsigned int)f2bf(r[1]) << 16);
        o.y = (unsigned int)f2bf(r[2]) | ((unsigned int)f2bf(r[3]) << 16);
        o.z = (unsigned int)f2bf(r[4]) | ((unsigned int)f2bf(r[5]) << 16);
        o.w = (unsigned int)f2bf(r[6]) | ((unsigned int)f2bf(r[7]) << 16);
        *(uint4*)(out + (size_t)wid * FDIM + q * 8) = o;
    }
}

// ---------------- layer 4 (H=1, D=10): GEMM fused with el/er; cls padded to 16 ----------------

__global__ void __launch_bounds__(256)
gemm4(const u16* __restrict__ A, const void* __restrict__ W,
      const void* __restrict__ alw, const void* __restrict__ arw,
      float* __restrict__ out, float* __restrict__ el, float* __restrict__ er,
      const int* __restrict__ dflag) {
    __shared__ float Wl[128][16];
    const bool isf32 = (*dflag != 0);
    for (int t = threadIdx.x; t < 128 * 16; t += 256) {
        int k = t >> 4, c = t & 15;
        Wl[k][c] = (c < NCLS) ? ldin(W, k * NCLS + c, isf32) : 0.f;
    }
    __syncthreads();
    int idx = blockIdx.x * 256 + threadIdx.x;
    int n = idx >> 4, c = idx & 15;
    if (n >= N_NODES) return;
    const u16* a = A + (size_t)n * FDIM;
    float acc = 0.f;
    #pragma unroll
    for (int q = 0; q < 32; q++) {
        float4 v = ld4f(a + q * 4);
        acc += v.x * Wl[q * 4 + 0][c] + v.y * Wl[q * 4 + 1][c] +
               v.z * Wl[q * 4 + 2][c] + v.w * Wl[q * 4 + 3][c];
    }
    out[n * CLSP + c] = acc;    // 64B-aligned padded row (c>=NCLS lanes write 0-weights result)
    float alc = (c < NCLS) ? ldin(alw, c, isf32) : 0.f;
    float arc = (c < NCLS) ? ldin(arw, c, isf32) : 0.f;
    float sl = acc * alc, sr = acc * arc;
    #pragma unroll
    for (int off = 8; off >= 1; off >>= 1) {
        sl += __shfl_xor(sl, off, 64);
        sr += __shfl_xor(sr, off, 64);
    }
    if (c == 0) { el[n] = sl; er[n] = sr; }
}

// ---------------- final aggregation: 4 nodes per wave (16 lanes each) ----------------

__global__ void __launch_bounds__(256)
agg4(const float* __restrict__ feat, const float* __restrict__ el,
     const float* __restrict__ er, const int* __restrict__ row_ptr,
     const u16* __restrict__ srcs, void* __restrict__ out,
     const int* __restrict__ dflag) {
    const bool isf32 = (*dflag != 0);
    int wid = (blockIdx.x * 256 + threadIdx.x) >> 6;
    int lane = threadIdx.x & 63;
    int g = lane >> 4, t = lane & 15;
    int node = wid * 4 + g;
    bool vn = node < N_NODES;
    int nn = vn ? node : 0;
    int beg = row_ptr[nn];
    int end = vn ? row_ptr[nn + 1] : beg;
    float ern = er[nn];
    int deg = end - beg;
    int mx = deg;
    mx = max(mx, __shfl_xor(mx, 16, 64));
    mx = max(mx, __shfl_xor(mx, 32, 64));
    float ssA = 0.f, ssB = 0.f, aA = 0.f, aB = 0.f;
    int k = 0;
    for (; k + 1 < mx; k += 2) {
        int i0 = beg + k, i1 = i0 + 1;
        bool v0 = i0 < end, v1 = i1 < end;
        int s0 = srcs[v0 ? i0 : beg];
        int s1 = srcs[v1 ? i1 : beg];
        float e0 = el[s0] + ern;
        float e1 = el[s1] + ern;
        float f0 = feat[s0 * CLSP + t];
        float f1 = feat[s1 * CLSP + t];
        e0 = fmaxf(e0, 0.2f * e0); e1 = fmaxf(e1, 0.2f * e1);
        float x0 = v0 ? __expf(fminf(e0, 80.f)) : 0.f;
        float x1 = v1 ? __expf(fminf(e1, 80.f)) : 0.f;
        ssA += x0; ssB += x1;
        aA = fmaf(x0, f0, aA);
        aB = fmaf(x1, f1, aB);
    }
    if (k < mx) {
        int i0 = beg + k;
        bool v0 = i0 < end;
        int s0 = srcs[v0 ? i0 : beg];
        float e0 = el[s0] + ern;
        e0 = fmaxf(e0, 0.2f * e0);
        float x0 = v0 ? __expf(fminf(e0, 80.f)) : 0.f;
        ssA += x0;
        aA = fmaf(x0, feat[s0 * CLSP + t], aA);
    }
    float ss = ssA + ssB, a = aA + aB;
    if (vn && t < NCLS) {
        float r = (deg > 0) ? a / ss : 0.f;
        if (isf32) ((float*)out)[node * NCLS + t] = r;
        else       ((u16*)out)[node * NCLS + t] = f2bf(r);
    }
}

// ---------------- launch ----------------

extern "C" void kernel_launch(void* const* d_in, const int* in_sizes, int n_in,
                              void* d_out, int out_size, void* d_ws, size_t ws_size,
                              hipStream_t stream) {
    const void* h_in = d_in[0];
    const int* src   = (const int*)d_in[1];
    const int* dst   = (const int*)d_in[2];
    const void *W[5], *al[5], *ar[5];
    for (int l = 0; l < 5; l++) {
        W[l]  = d_in[3 + 3 * l];
        al[l] = d_in[4 + 3 * l];
        ar[l] = d_in[5 + 3 * l];
    }

    char* ws = (char*)d_ws;
    size_t off = 0;
    auto alloc = [&](size_t bytes) {
        void* p = ws + off;
        off = (off + bytes + 255) & ~(size_t)255;
        return p;
    };
    int* dflag   = (int*)alloc(4);
    u16* bufA    = (u16*)alloc((size_t)N_NODES * FDIM * sizeof(u16)); // agg output / GEMM input (bf16)
    u16* bufB    = (u16*)alloc((size_t)N_NODES * FDIM * sizeof(u16)); // post-GEMM feat (gather target)
    u16* Wt      = (u16*)alloc(4ull * FDIM * FDIM * sizeof(u16));     // transposed bf16 weights
    float* elb   = (float*)alloc((size_t)N_NODES * HEADS * 4);
    float* erb   = (float*)alloc((size_t)N_NODES * HEADS * 4);
    float* cls   = (float*)alloc((size_t)N_NODES * CLSP * 4);
    int* deg     = (int*)alloc((size_t)N_NODES * 4);
    int* row_ptr = (int*)alloc((size_t)(N_NODES + 1) * 4);
    int* cursor  = (int*)alloc((size_t)N_NODES * 4);
    u16* srcs    = (u16*)alloc((size_t)N_EDGES * 2);
    int* bsum    = (int*)alloc(256 * 4);

    const int NB = (N_NODES + SCB - 1) / SCB;   // 98 scan blocks

    detect_dtype<<<1, 256, 0, stream>>>((const u16*)W[0], FDIM * FDIM, dflag);
    prep_wt<<<dim3((FDIM * FDIM + 255) / 256, 4), 256, 0, stream>>>(
        W[0], W[1], W[2], W[3], Wt, dflag);

    zero_int<<<(N_NODES + 255) / 256, 256, 0, stream>>>(deg, N_NODES);
    count_deg<<<(N_EDGES + 255) / 256, 256, 0, stream>>>(dst, deg);
    deg_bsum<<<NB, SCB, 0, stream>>>(deg, bsum);
    scan_bsum<<<1, 64, 0, stream>>>(bsum, NB, row_ptr);
    deg_scan<<<NB, SCB, 0, stream>>>(deg, bsum, row_ptr, cursor);
    const int BPP = 256;   // blocks per partition (2048 blocks total, ~8/CU)
    fill_csr_x<<<NPART * BPP, 256, 0, stream>>>(src, dst, cursor, srcs, BPP);

    for (int l = 0; l < 4; l++) {
        if (l == 0)
            gemm_mfma<true><<<(N_NODES + 31) / 32, 256, 0, stream>>>(
                h_in, Wt, al[0], ar[0], bufB, elb, erb, dflag, N_NODES);
        else
            gemm_mfma<false><<<(N_NODES + 31) / 32, 256, 0, stream>>>(
                bufA, Wt + l * FDIM * FDIM, al[l], ar[l], bufB, elb, erb, dflag, N_NODES);
        agg_attn<true><<<(N_NODES + 3) / 4, 256, 0, stream>>>(
            bufB, elb, erb, row_ptr, srcs, bufA);
    }
    gemm4<<<(N_NODES * 16 + 255) / 256, 256, 0, stream>>>(
        bufA, W[4], al[4], ar[4], cls, elb, erb, dflag);
    agg4<<<(N_NODES / 16 + 1), 256, 0, stream>>>(cls, elb, erb, row_ptr, srcs, d_out, dflag);
}

// Round 10
// 442.636 us; speedup vs baseline: 1.0956x; 1.0150x over previous
//
#include <hip/hip_runtime.h>
#include <hip/hip_bf16.h>

#define N_NODES 50000
#define N_EDGES 800000
#define FDIM    128
#define HEADS   8
#define HID     16
#define NCLS    10
#define CLSP    16    // padded cls row (64B aligned)
#define SCB     512   // scan block size
#define NPART   8     // XCD partitions for CSR scatter/count
#define PSZ     6250  // N_NODES / NPART
#define GROWS   64    // gemm rows per block

typedef unsigned short u16;
typedef __attribute__((ext_vector_type(8))) short bf16x8;
typedef __attribute__((ext_vector_type(4))) float f32x4;

__device__ __forceinline__ float bf2f(u16 u) {
    union { unsigned int i; float f; } c; c.i = ((unsigned int)u) << 16; return c.f;
}
__device__ __forceinline__ float bf2f_hi(unsigned int u) {
    union { unsigned int i; float f; } c; c.i = u & 0xffff0000u; return c.f;
}
__device__ __forceinline__ float bf2f_lo(unsigned int u) {
    union { unsigned int i; float f; } c; c.i = u << 16; return c.f;
}
__device__ __forceinline__ u16 f2bf(float f) {
    union { float f; unsigned int i; } c; c.f = f;
    unsigned int r = c.i + 0x7FFFu + ((c.i >> 16) & 1u);
    return (u16)(r >> 16);
}
__device__ __forceinline__ float4 bf2f4(ushort4 u) {
    return make_float4(bf2f(u.x), bf2f(u.y), bf2f(u.z), bf2f(u.w));
}
__device__ __forceinline__ float4 ld4f(const u16* p)  { return bf2f4(*(const ushort4*)p); }
__device__ __forceinline__ void   st4(u16* p, float4 v) {
    ushort4 u; u.x = f2bf(v.x); u.y = f2bf(v.y); u.z = f2bf(v.z); u.w = f2bf(v.w);
    *(ushort4*)p = u;
}

// external-input decode (dtype resolved at runtime via flag)
__device__ __forceinline__ float ldin(const void* p, int i, bool isf32) {
    return isf32 ? ((const float*)p)[i] : bf2f(((const u16*)p)[i]);
}
__device__ __forceinline__ float4 ldin4(const void* p, int i4, bool isf32) {
    if (isf32) return ((const float4*)p)[i4];
    return bf2f4(((const ushort4*)p)[i4]);
}

// ---------------- dtype detection (W0 scan) ----------------
__global__ void detect_dtype(const u16* __restrict__ w, int n, int* __restrict__ flag) {
    __shared__ int s_huge, s_zero;
    if (threadIdx.x == 0) { s_huge = 0; s_zero = 0; }
    __syncthreads();
    int huge = 0, zero = 0;
    for (int i = threadIdx.x; i < n; i += 256) {
        u16 b = w[i];
        float v = bf2f(b);
        if (fabsf(v) > 1e9f || v != v) huge++;
        if (b == 0) zero++;
    }
    atomicAdd(&s_huge, huge);
    atomicAdd(&s_zero, zero);
    __syncthreads();
    if (threadIdx.x == 0)
        *flag = (s_huge > 0 || s_zero > n / 4) ? 1 : 0;
}

// ---------------- W transpose to bf16 (Wt[n][k]) for MFMA B-frags ----------------
__global__ void prep_wt(const void* __restrict__ W0, const void* __restrict__ W1,
                        const void* __restrict__ W2, const void* __restrict__ W3,
                        u16* __restrict__ Wt, const int* __restrict__ dflag) {
    const bool isf32 = (*dflag != 0);
    int l = blockIdx.y;
    const void* W = (l == 0) ? W0 : (l == 1) ? W1 : (l == 2) ? W2 : W3;
    int i = blockIdx.x * 256 + threadIdx.x;
    if (i >= FDIM * FDIM) return;
    int n = i >> 7, k = i & 127;
    Wt[l * FDIM * FDIM + n * FDIM + k] = f2bf(ldin(W, k * FDIM + n, isf32));
}

// ---------------- CSR build ----------------

__global__ void zero_int(int* p, int n) {
    int i = blockIdx.x * blockDim.x + threadIdx.x;
    if (i < n) p[i] = 0;
}

// XCD-partitioned degree count (atomics stay in one XCD's L2)
__global__ void __launch_bounds__(256)
count_deg_x(const int* __restrict__ dst, int* __restrict__ deg, int blocksPerPart) {
    int part = blockIdx.x & (NPART - 1);
    int sub  = blockIdx.x >> 3;
    int lo = part * PSZ, hi = lo + PSZ;
    int stride = blocksPerPart * 256;
    for (int i = sub * 256 + threadIdx.x; i < N_EDGES; i += stride) {
        int d = __builtin_nontemporal_load(&dst[i]);
        if (d >= lo && d < hi) atomicAdd(&deg[d], 1);
    }
}

__global__ void __launch_bounds__(SCB)
deg_bsum(const int* __restrict__ deg, int* __restrict__ bsum) {
    int i = blockIdx.x * SCB + threadIdx.x;
    int v = (i < N_NODES) ? deg[i] : 0;
    for (int off = 32; off; off >>= 1) v += __shfl_down(v, off, 64);
    __shared__ int wsum[SCB / 64];
    int wv = threadIdx.x >> 6, ln = threadIdx.x & 63;
    if (ln == 0) wsum[wv] = v;
    __syncthreads();
    if (threadIdx.x == 0) {
        int s = 0;
        #pragma unroll
        for (int k = 0; k < SCB / 64; k++) s += wsum[k];
        bsum[blockIdx.x] = s;
    }
}

__global__ void scan_bsum(int* __restrict__ bsum, int nb, int* __restrict__ row_ptr) {
    int ln = threadIdx.x;  // 64 threads, nb <= 128
    int o0 = (ln < nb) ? bsum[ln] : 0;
    int o1 = (64 + ln < nb) ? bsum[64 + ln] : 0;
    int v0 = o0, v1 = o1;
    for (int d = 1; d < 64; d <<= 1) { int t = __shfl_up(v0, d, 64); if (ln >= d) v0 += t; }
    int tot0 = __shfl(v0, 63, 64);
    for (int d = 1; d < 64; d <<= 1) { int t = __shfl_up(v1, d, 64); if (ln >= d) v1 += t; }
    v1 += tot0;
    if (ln < nb) bsum[ln] = v0 - o0;
    if (64 + ln < nb) bsum[64 + ln] = v1 - o1;
    if (ln == 0) row_ptr[N_NODES] = N_EDGES;
}

__global__ void __launch_bounds__(SCB)
deg_scan(const int* __restrict__ deg, const int* __restrict__ bsum,
         int* __restrict__ row_ptr, int* __restrict__ cursor) {
    __shared__ int sd[SCB];
    int tid = threadIdx.x;
    int i = blockIdx.x * SCB + tid;
    int v = (i < N_NODES) ? deg[i] : 0;
    sd[tid] = v;
    __syncthreads();
    for (int off = 1; off < SCB; off <<= 1) {
        int t = (tid >= off) ? sd[tid - off] : 0;
        __syncthreads();
        sd[tid] += t;
        __syncthreads();
    }
    if (i < N_NODES) {
        int ex = sd[tid] - v + bsum[blockIdx.x];
        row_ptr[i] = ex;
        cursor[i] = ex;
    }
}

// XCD-partitioned scatter into u16 srcs (node ids < 65536).
__global__ void __launch_bounds__(256)
fill_csr_x(const int* __restrict__ src, const int* __restrict__ dst,
           int* __restrict__ cursor, u16* __restrict__ srcs, int blocksPerPart) {
    int part = blockIdx.x & (NPART - 1);
    int sub  = blockIdx.x >> 3;
    int lo = part * PSZ, hi = lo + PSZ;
    int stride = blocksPerPart * 256;
    for (int i = sub * 256 + threadIdx.x; i < N_EDGES; i += stride) {
        int d = __builtin_nontemporal_load(&dst[i]);
        if (d >= lo && d < hi) {
            int pos = atomicAdd(&cursor[d], 1);
            srcs[pos] = (u16)__builtin_nontemporal_load(&src[i]);
        }
    }
}

// ---------------- MFMA GEMM + fused el/er ----------------
// C[N,128] = A[N,128] @ W[128,128]; block = 64 rows, 4 waves (wave w -> cols w*32..+31).
// EXT=true: A is the external input (decode via dflag); else A is bf16 workspace.

template<bool EXT>
__global__ void __launch_bounds__(256)
gemm_mfma(const void* __restrict__ A, const u16* __restrict__ Wt,
          const void* __restrict__ alw, const void* __restrict__ arw,
          u16* __restrict__ C, float* __restrict__ el, float* __restrict__ er,
          const int* __restrict__ dflag, int nrows) {
    __shared__ __align__(16) char smem[GROWS * 132 * 4];  // Ct fp32 (33792 B) aliases As bf16 (17408 B)
    u16   (*As)[136] = (u16(*)[136])smem;
    float (*Ct)[132] = (float(*)[132])smem;
    __shared__ u16 alv[128], arv[128];
    const bool isf32 = (*dflag != 0);
    int tid = threadIdx.x;
    if (tid < 128) {
        alv[tid] = f2bf(ldin(alw, tid, isf32));
        arv[tid] = f2bf(ldin(arw, tid, isf32));
    }
    int rowBase = blockIdx.x * GROWS;
    for (int t = tid; t < GROWS * 32; t += 256) {
        int r = t >> 5, q = t & 31;
        int n = rowBase + r;
        if (EXT) {
            float4 v = make_float4(0.f, 0.f, 0.f, 0.f);
            if (n < nrows) v = ldin4(A, n * 32 + q, isf32);
            ushort4 u; u.x = f2bf(v.x); u.y = f2bf(v.y); u.z = f2bf(v.z); u.w = f2bf(v.w);
            *(ushort4*)&As[r][q * 4] = u;
        } else {
            ushort4 u = make_ushort4(0, 0, 0, 0);
            if (n < nrows) u = *(const ushort4*)((const u16*)A + (size_t)n * FDIM + q * 4);
            *(ushort4*)&As[r][q * 4] = u;
        }
    }
    int wv = tid >> 6, ln = tid & 63;
    int ln15 = ln & 15, quad = ln >> 4;
    bf16x8 bfr[2][4];
    #pragma unroll
    for (int c = 0; c < 2; c++)
        #pragma unroll
        for (int kk = 0; kk < 4; kk++)
            bfr[c][kk] = *(const bf16x8*)(Wt + (wv * 32 + c * 16 + ln15) * FDIM + kk * 32 + quad * 8);
    __syncthreads();
    f32x4 acc[4][2] = {};   // [row-tile][col-tile]
    #pragma unroll
    for (int kk = 0; kk < 4; kk++) {
        #pragma unroll
        for (int rt = 0; rt < 4; rt++) {
            bf16x8 a = *(const bf16x8*)&As[rt * 16 + ln15][kk * 32 + quad * 8];
            acc[rt][0] = __builtin_amdgcn_mfma_f32_16x16x32_bf16(a, bfr[0][kk], acc[rt][0], 0, 0, 0);
            acc[rt][1] = __builtin_amdgcn_mfma_f32_16x16x32_bf16(a, bfr[1][kk], acc[rt][1], 0, 0, 0);
        }
    }
    __syncthreads();   // all As reads done; smem becomes Ct
    #pragma unroll
    for (int rt = 0; rt < 4; rt++)
        #pragma unroll
        for (int c = 0; c < 2; c++)
            #pragma unroll
            for (int p = 0; p < 4; p++)
                Ct[rt * 16 + quad * 4 + p][wv * 32 + c * 16 + ln15] = acc[rt][c][p];
    __syncthreads();
    // coalesced bf16 C store: each thread stores 8 rows x 4 cols
    int jc = (tid & 31) * 4, r0 = (tid >> 5) * 8;
    #pragma unroll
    for (int r = 0; r < 8; r++) {
        int n = rowBase + r0 + r;
        if (n < nrows)
            st4(C + (size_t)n * FDIM + jc, *(const float4*)&Ct[r0 + r][jc]);
    }
    // fused el/er: 64 rows x 8 heads = 512 items, 2 per thread
    int head = tid & 7;
    #pragma unroll
    for (int rr = 0; rr < 2; rr++) {
        int row = (tid >> 3) + rr * 32;
        int n2 = rowBase + row;
        if (n2 < nrows) {
            float sl = 0.f, sr = 0.f;
            #pragma unroll
            for (int k = 0; k < HID; k++) {
                float v = Ct[row][head * HID + k];
                sl += v * bf2f(alv[head * HID + k]);
                sr += v * bf2f(arv[head * HID + k]);
            }
            el[n2 * HEADS + head] = sl;
            er[n2 * HEADS + head] = sr;
        }
    }
}

// ---------------- attention aggregation: 1 node/wave, 8 edge slots x 8 lanes ----------------
// lane = (g=lane>>3: edge slot, q=lane&7: head / 32B column block q*16..q*16+15).
// 8 edges in flight per wave; tail predicated (x=0). Reduce slots via shfl_xor(8/16/32).

template<bool ACT>
__global__ void __launch_bounds__(256)
agg_attn(const u16* __restrict__ feat, const float* __restrict__ el,
         const float* __restrict__ er, const int* __restrict__ row_ptr,
         const u16* __restrict__ srcs, u16* __restrict__ out) {
    int wid = (blockIdx.x * 256 + threadIdx.x) >> 6;
    int lane = threadIdx.x & 63;
    if (wid >= N_NODES) return;
    int g = lane >> 3;           // edge slot 0..7
    int q = lane & 7;            // head == column block (cols q*16 .. q*16+15)
    int beg = row_ptr[wid], end = row_ptr[wid + 1];
    float ern = er[wid * HEADS + q];
    float ss = 0.f;
    float acc[16] = {};
    for (int i = beg; i < end; i += 8) {
        int idx = i + g;
        bool v = idx < end;
        int s = srcs[v ? idx : beg];
        float e = el[s * HEADS + q] + ern;
        e = fmaxf(e, 0.2f * e);
        float x = v ? __expf(fminf(e, 80.f)) : 0.f;
        const u16* fr = feat + (size_t)s * FDIM + q * 16;
        uint4 u0 = *(const uint4*)fr;
        uint4 u1 = *(const uint4*)(fr + 8);
        ss += x;
        acc[0]  = fmaf(x, bf2f_lo(u0.x), acc[0]);  acc[1]  = fmaf(x, bf2f_hi(u0.x), acc[1]);
        acc[2]  = fmaf(x, bf2f_lo(u0.y), acc[2]);  acc[3]  = fmaf(x, bf2f_hi(u0.y), acc[3]);
        acc[4]  = fmaf(x, bf2f_lo(u0.z), acc[4]);  acc[5]  = fmaf(x, bf2f_hi(u0.z), acc[5]);
        acc[6]  = fmaf(x, bf2f_lo(u0.w), acc[6]);  acc[7]  = fmaf(x, bf2f_hi(u0.w), acc[7]);
        acc[8]  = fmaf(x, bf2f_lo(u1.x), acc[8]);  acc[9]  = fmaf(x, bf2f_hi(u1.x), acc[9]);
        acc[10] = fmaf(x, bf2f_lo(u1.y), acc[10]); acc[11] = fmaf(x, bf2f_hi(u1.y), acc[11]);
        acc[12] = fmaf(x, bf2f_lo(u1.z), acc[12]); acc[13] = fmaf(x, bf2f_hi(u1.z), acc[13]);
        acc[14] = fmaf(x, bf2f_lo(u1.w), acc[14]); acc[15] = fmaf(x, bf2f_hi(u1.w), acc[15]);
    }
    ss += __shfl_xor(ss, 8, 64);
    ss += __shfl_xor(ss, 16, 64);
    ss += __shfl_xor(ss, 32, 64);
    #pragma unroll
    for (int k = 0; k < 16; k++) {
        acc[k] += __shfl_xor(acc[k], 8, 64);
        acc[k] += __shfl_xor(acc[k], 16, 64);
        acc[k] += __shfl_xor(acc[k], 32, 64);
    }
    if (g == 0) {
        float inv = (end > beg) ? 1.f / ss : 0.f;
        float r[16];
        #pragma unroll
        for (int k = 0; k < 16; k++) {
            float t = acc[k] * inv;
            if (ACT) t = (t > 0.f) ? t : (__expf(t) - 1.f);   // ELU
            r[k] = t;
        }
        uint4 o0, o1;
        o0.x = (unsigned int)f2bf(r[0])  | ((unsigned int)f2bf(r[1])  << 16);
        o0.y = (unsigned int)f2bf(r[2])  | ((unsigned int)f2bf(r[3])  << 16);
        o0.z = (unsigned int)f2bf(r[4])  | ((unsigned int)f2bf(r[5])  << 16);
        o0.w = (unsigned int)f2bf(r[6])  | ((unsigned int)f2bf(r[7])  << 16);
        o1.x = (unsigned int)f2bf(r[8])  | ((unsigned int)f2bf(r[9])  << 16);
        o1.y = (unsigned int)f2bf(r[10]) | ((unsigned int)f2bf(r[11]) << 16);
        o1.z = (unsigned int)f2bf(r[12]) | ((unsigned int)f2bf(r[13]) << 16);
        o1.w = (unsigned int)f2bf(r[14]) | ((unsigned int)f2bf(r[15]) << 16);
        u16* ob = out + (size_t)wid * FDIM + q * 16;
        *(uint4*)ob = o0;
        *(uint4*)(ob + 8) = o1;
    }
}

// ---------------- layer 4 (H=1, D=10): GEMM fused with el/er; cls padded to 16 ----------------

__global__ void __launch_bounds__(256)
gemm4(const u16* __restrict__ A, const void* __restrict__ W,
      const void* __restrict__ alw, const void* __restrict__ arw,
      float* __restrict__ out, float* __restrict__ el, float* __restrict__ er,
      const int* __restrict__ dflag) {
    __shared__ float Wl[128][16];
    const bool isf32 = (*dflag != 0);
    for (int t = threadIdx.x; t < 128 * 16; t += 256) {
        int k = t >> 4, c = t & 15;
        Wl[k][c] = (c < NCLS) ? ldin(W, k * NCLS + c, isf32) : 0.f;
    }
    __syncthreads();
    int idx = blockIdx.x * 256 + threadIdx.x;
    int n = idx >> 4, c = idx & 15;
    if (n >= N_NODES) return;
    const u16* a = A + (size_t)n * FDIM;
    float acc = 0.f;
    #pragma unroll
    for (int q = 0; q < 32; q++) {
        float4 v = ld4f(a + q * 4);
        acc += v.x * Wl[q * 4 + 0][c] + v.y * Wl[q * 4 + 1][c] +
               v.z * Wl[q * 4 + 2][c] + v.w * Wl[q * 4 + 3][c];
    }
    out[n * CLSP + c] = acc;    // 64B-aligned padded row
    float alc = (c < NCLS) ? ldin(alw, c, isf32) : 0.f;
    float arc = (c < NCLS) ? ldin(arw, c, isf32) : 0.f;
    float sl = acc * alc, sr = acc * arc;
    #pragma unroll
    for (int off = 8; off >= 1; off >>= 1) {
        sl += __shfl_xor(sl, off, 64);
        sr += __shfl_xor(sr, off, 64);
    }
    if (c == 0) { el[n] = sl; er[n] = sr; }
}

// ---------------- final aggregation: 4 nodes per wave (16 lanes each) ----------------

__global__ void __launch_bounds__(256)
agg4(const float* __restrict__ feat, const float* __restrict__ el,
     const float* __restrict__ er, const int* __restrict__ row_ptr,
     const u16* __restrict__ srcs, void* __restrict__ out,
     const int* __restrict__ dflag) {
    const bool isf32 = (*dflag != 0);
    int wid = (blockIdx.x * 256 + threadIdx.x) >> 6;
    int lane = threadIdx.x & 63;
    int g = lane >> 4, t = lane & 15;
    int node = wid * 4 + g;
    bool vn = node < N_NODES;
    int nn = vn ? node : 0;
    int beg = row_ptr[nn];
    int end = vn ? row_ptr[nn + 1] : beg;
    float ern = er[nn];
    int deg = end - beg;
    int mx = deg;
    mx = max(mx, __shfl_xor(mx, 16, 64));
    mx = max(mx, __shfl_xor(mx, 32, 64));
    float ssA = 0.f, ssB = 0.f, aA = 0.f, aB = 0.f;
    int k = 0;
    for (; k + 1 < mx; k += 2) {
        int i0 = beg + k, i1 = i0 + 1;
        bool v0 = i0 < end, v1 = i1 < end;
        int s0 = srcs[v0 ? i0 : beg];
        int s1 = srcs[v1 ? i1 : beg];
        float e0 = el[s0] + ern;
        float e1 = el[s1] + ern;
        float f0 = feat[s0 * CLSP + t];
        float f1 = feat[s1 * CLSP + t];
        e0 = fmaxf(e0, 0.2f * e0); e1 = fmaxf(e1, 0.2f * e1);
        float x0 = v0 ? __expf(fminf(e0, 80.f)) : 0.f;
        float x1 = v1 ? __expf(fminf(e1, 80.f)) : 0.f;
        ssA += x0; ssB += x1;
        aA = fmaf(x0, f0, aA);
        aB = fmaf(x1, f1, aB);
    }
    if (k < mx) {
        int i0 = beg + k;
        bool v0 = i0 < end;
        int s0 = srcs[v0 ? i0 : beg];
        float e0 = el[s0] + ern;
        e0 = fmaxf(e0, 0.2f * e0);
        float x0 = v0 ? __expf(fminf(e0, 80.f)) : 0.f;
        ssA += x0;
        aA = fmaf(x0, feat[s0 * CLSP + t], aA);
    }
    float ss = ssA + ssB, a = aA + aB;
    if (vn && t < NCLS) {
        float r = (deg > 0) ? a / ss : 0.f;
        if (isf32) ((float*)out)[node * NCLS + t] = r;
        else       ((u16*)out)[node * NCLS + t] = f2bf(r);
    }
}

// ---------------- launch ----------------

extern "C" void kernel_launch(void* const* d_in, const int* in_sizes, int n_in,
                              void* d_out, int out_size, void* d_ws, size_t ws_size,
                              hipStream_t stream) {
    const void* h_in = d_in[0];
    const int* src   = (const int*)d_in[1];
    const int* dst   = (const int*)d_in[2];
    const void *W[5], *al[5], *ar[5];
    for (int l = 0; l < 5; l++) {
        W[l]  = d_in[3 + 3 * l];
        al[l] = d_in[4 + 3 * l];
        ar[l] = d_in[5 + 3 * l];
    }

    char* ws = (char*)d_ws;
    size_t off = 0;
    auto alloc = [&](size_t bytes) {
        void* p = ws + off;
        off = (off + bytes + 255) & ~(size_t)255;
        return p;
    };
    int* dflag   = (int*)alloc(4);
    u16* bufA    = (u16*)alloc((size_t)N_NODES * FDIM * sizeof(u16)); // agg output / GEMM input (bf16)
    u16* bufB    = (u16*)alloc((size_t)N_NODES * FDIM * sizeof(u16)); // post-GEMM feat (gather target)
    u16* Wt      = (u16*)alloc(4ull * FDIM * FDIM * sizeof(u16));     // transposed bf16 weights
    float* elb   = (float*)alloc((size_t)N_NODES * HEADS * 4);
    float* erb   = (float*)alloc((size_t)N_NODES * HEADS * 4);
    float* cls   = (float*)alloc((size_t)N_NODES * CLSP * 4);
    int* deg     = (int*)alloc((size_t)N_NODES * 4);
    int* row_ptr = (int*)alloc((size_t)(N_NODES + 1) * 4);
    int* cursor  = (int*)alloc((size_t)N_NODES * 4);
    u16* srcs    = (u16*)alloc((size_t)N_EDGES * 2);
    int* bsum    = (int*)alloc(256 * 4);

    const int NB = (N_NODES + SCB - 1) / SCB;   // 98 scan blocks

    detect_dtype<<<1, 256, 0, stream>>>((const u16*)W[0], FDIM * FDIM, dflag);
    prep_wt<<<dim3((FDIM * FDIM + 255) / 256, 4), 256, 0, stream>>>(
        W[0], W[1], W[2], W[3], Wt, dflag);

    zero_int<<<(N_NODES + 255) / 256, 256, 0, stream>>>(deg, N_NODES);
    const int CPP = 128;   // count blocks per partition
    count_deg_x<<<NPART * CPP, 256, 0, stream>>>(dst, deg, CPP);
    deg_bsum<<<NB, SCB, 0, stream>>>(deg, bsum);
    scan_bsum<<<1, 64, 0, stream>>>(bsum, NB, row_ptr);
    deg_scan<<<NB, SCB, 0, stream>>>(deg, bsum, row_ptr, cursor);
    const int BPP = 256;   // fill blocks per partition
    fill_csr_x<<<NPART * BPP, 256, 0, stream>>>(src, dst, cursor, srcs, BPP);

    for (int l = 0; l < 4; l++) {
        if (l == 0)
            gemm_mfma<true><<<(N_NODES + GROWS - 1) / GROWS, 256, 0, stream>>>(
                h_in, Wt, al[0], ar[0], bufB, elb, erb, dflag, N_NODES);
        else
            gemm_mfma<false><<<(N_NODES + GROWS - 1) / GROWS, 256, 0, stream>>>(
                bufA, Wt + l * FDIM * FDIM, al[l], ar[l], bufB, elb, erb, dflag, N_NODES);
        agg_attn<true><<<(N_NODES + 3) / 4, 256, 0, stream>>>(
            bufB, elb, erb, row_ptr, srcs, bufA);
    }
    gemm4<<<(N_NODES * 16 + 255) / 256, 256, 0, stream>>>(
        bufA, W[4], al[4], ar[4], cls, elb, erb, dflag);
    agg4<<<(N_NODES / 16 + 1), 256, 0, stream>>>(cls, elb, erb, row_ptr, srcs, d_out, dflag);
}